// Round 1
// baseline (10387.527 us; speedup 1.0000x reference)
//
#include <hip/hip_runtime.h>

#define DD 48
#define HF 256
#define WF 320
#define HH 128
#define WH 160
#define NPF (HF * WF)   // 81920
#define NPH (HH * WH)   // 20480

__device__ __forceinline__ float sigf(float x) {
    return 1.0f / (1.0f + __expf(-x));
}
__device__ __forceinline__ float tanh_(float x) {
    // 1 - 2/(e^{2x}+1): monotone, saturates to +/-1 without NaN at large |x|
    float e = __expf(2.0f * x);
    return 1.0f - 2.0f / (e + 1.0f);
}

// Accumulate a 3x3 (pad=1, stride=1) conv over CBLK input channels into acc[COUT].
// in: pointer to channel 0 of this block, channel stride = cstride elements.
// w: pointer to w[co0][ci0][0][0]; wcs = element stride between consecutive couts.
// Weight indices are block-uniform -> scalar loads.
template<int CBLK, int COUT, int Ht, int Wt>
__device__ __forceinline__ void conv_block(
    const float* __restrict__ in, long cstride,
    const float* __restrict__ w, int wcs,
    int y, int xx, float* acc)
{
    const bool ym = y > 0, yp = y < Ht - 1, xm = xx > 0, xp = xx < Wt - 1;
    const float* ctr = in + (long)y * Wt + xx;
#pragma unroll 4
    for (int ci = 0; ci < CBLK; ++ci) {
        const float* p = ctr + (long)ci * cstride;
        float v[9];
        v[0] = (ym && xm) ? p[-Wt - 1] : 0.f;
        v[1] = ym ? p[-Wt] : 0.f;
        v[2] = (ym && xp) ? p[-Wt + 1] : 0.f;
        v[3] = xm ? p[-1] : 0.f;
        v[4] = p[0];
        v[5] = xp ? p[1] : 0.f;
        v[6] = (yp && xm) ? p[Wt - 1] : 0.f;
        v[7] = yp ? p[Wt] : 0.f;
        v[8] = (yp && xp) ? p[Wt + 1] : 0.f;
        const float* wp = w + ci * 9;
#pragma unroll
        for (int j = 0; j < COUT; ++j) {
            const float* wc = wp + j * wcs;
#pragma unroll
            for (int k = 0; k < 9; ++k) acc[j] = fmaf(v[k], wc[k], acc[j]);
        }
    }
}

// conv1: x slice d (32 ch, channel stride DD*NPF) -> relu -> out (8, HF, WF).
// Batched over blockIdx.z (d = d0 + z), out += z * odstride.
__global__ __launch_bounds__(256) void k_conv1(
    const float* __restrict__ x, const float* __restrict__ w,
    const float* __restrict__ b, float* __restrict__ out,
    int d0, long odstride)
{
    const int pix = blockIdx.x * 256 + threadIdx.x;
    const int y = pix / WF, xx = pix - y * WF;
    const long d = d0 + blockIdx.z;
    const float* xin = x + d * (long)NPF;
    float acc[8];
#pragma unroll
    for (int j = 0; j < 8; ++j) acc[j] = b[j];
    conv_block<32, 8, HF, WF>(xin, (long)DD * NPF, w, 32 * 9, y, xx, acc);
    float* o = out + blockIdx.z * odstride + pix;
#pragma unroll
    for (int j = 0; j < 8; ++j) o[(long)j * NPF] = fmaxf(acc[j], 0.f);
}

// gates: g = sigmoid(conv(cat(a, s), w) + b), w is (2C, 2C, 3, 3).
// blockIdx.y selects an 8-wide cout chunk; chunks with co0 < C emit rh = sig*s,
// chunks with co0 >= C emit u = sig.
template<int C, int Ht, int Wt>
__global__ __launch_bounds__(256) void k_gates(
    const float* __restrict__ a, const float* __restrict__ s,
    const float* __restrict__ w, const float* __restrict__ b,
    float* __restrict__ rh, float* __restrict__ u)
{
    const int NP = Ht * Wt;
    const int pix = blockIdx.x * 256 + threadIdx.x;
    const int y = pix / Wt, xx = pix - y * Wt;
    const int co0 = blockIdx.y * 8;
    float acc[8];
#pragma unroll
    for (int j = 0; j < 8; ++j) acc[j] = b[co0 + j];
    conv_block<C, 8, Ht, Wt>(a, NP, w + (long)co0 * (2 * C) * 9, 2 * C * 9, y, xx, acc);
    conv_block<C, 8, Ht, Wt>(s, NP, w + ((long)co0 * (2 * C) + C) * 9, 2 * C * 9, y, xx, acc);
    if (co0 < C) {
#pragma unroll
        for (int j = 0; j < 8; ++j) {
            long o = (long)(co0 + j) * NP + pix;
            rh[o] = sigf(acc[j]) * s[o];
        }
    } else {
#pragma unroll
        for (int j = 0; j < 8; ++j) {
            long o = (long)(co0 - C + j) * NP + pix;
            u[o] = sigf(acc[j]);
        }
    }
}

// cand + state update: c = tanh(conv(cat(a, rh), w) + b); s = u*s + (1-u)*c (in place).
// w is (C, 2C, 3, 3). blockIdx.y = 8-wide cout chunk.
template<int C, int Ht, int Wt>
__global__ __launch_bounds__(256) void k_cand(
    const float* __restrict__ a, const float* __restrict__ rh,
    const float* __restrict__ w, const float* __restrict__ b,
    const float* __restrict__ u, float* __restrict__ s)
{
    const int NP = Ht * Wt;
    const int pix = blockIdx.x * 256 + threadIdx.x;
    const int y = pix / Wt, xx = pix - y * Wt;
    const int co0 = blockIdx.y * 8;
    float acc[8];
#pragma unroll
    for (int j = 0; j < 8; ++j) acc[j] = b[co0 + j];
    conv_block<C, 8, Ht, Wt>(a, NP, w + (long)co0 * (2 * C) * 9, 2 * C * 9, y, xx, acc);
    conv_block<C, 8, Ht, Wt>(rh, NP, w + ((long)co0 * (2 * C) + C) * 9, 2 * C * 9, y, xx, acc);
#pragma unroll
    for (int j = 0; j < 8; ++j) {
        long o = (long)(co0 + j) * NP + pix;
        float c = tanh_(acc[j]);
        float uu = u[o];
        s[o] = fmaf(uu, s[o] - c, c);
    }
}

// conv2: stride-2 3x3, pad 1: s1 (8, HF, WF) -> relu -> c2 (16, HH, WH). w (16,8,3,3).
__global__ __launch_bounds__(256) void k_conv2(
    const float* __restrict__ s1, const float* __restrict__ w,
    const float* __restrict__ b, float* __restrict__ c2)
{
    const int pix = blockIdx.x * 256 + threadIdx.x;  // < NPH
    const int y = pix / WH, xx = pix - y * WH;
    const int co0 = blockIdx.y * 8;
    float acc[8];
#pragma unroll
    for (int j = 0; j < 8; ++j) acc[j] = b[co0 + j];
    const int iy0 = 2 * y - 1, ix0 = 2 * xx - 1;
#pragma unroll 4
    for (int ci = 0; ci < 8; ++ci) {
        const float* p = s1 + (long)ci * NPF;
        float v[9];
#pragma unroll
        for (int ky = 0; ky < 3; ++ky) {
            int iy = iy0 + ky;
            bool rok = (unsigned)iy < HF;
#pragma unroll
            for (int kx = 0; kx < 3; ++kx) {
                int ix = ix0 + kx;
                v[ky * 3 + kx] = (rok && (unsigned)ix < WF) ? p[(long)iy * WF + ix] : 0.f;
            }
        }
        const float* wp = w + ci * 9;
#pragma unroll
        for (int j = 0; j < 8; ++j) {
            const float* wc = wp + (co0 + j) * 8 * 9;
#pragma unroll
            for (int k = 0; k < 9; ++k) acc[j] = fmaf(v[k], wc[k], acc[j]);
        }
    }
#pragma unroll
    for (int j = 0; j < 8; ++j) c2[(long)(co0 + j) * NPH + pix] = fmaxf(acc[j], 0.f);
}

// up1: ConvTranspose2d(16->8, k=3, s=2, p=1, op=1) on s2 (16,HH,WH) -> (8,HF,WF),
// + s1 skip add + relu -> ubuf. w layout (I=16, O=8, 3, 3). One thread = 2x2 output quad.
__global__ __launch_bounds__(256) void k_up1(
    const float* __restrict__ s2, const float* __restrict__ w,
    const float* __restrict__ b, const float* __restrict__ s1,
    float* __restrict__ ubuf)
{
    const int q = blockIdx.x * 256 + threadIdx.x;  // < NPH
    const int r = q / WH, c = q - r * WH;
    float a00[8], a01[8], a10[8], a11[8];
#pragma unroll
    for (int j = 0; j < 8; ++j) { a00[j] = b[j]; a01[j] = b[j]; a10[j] = b[j]; a11[j] = b[j]; }
    const bool cp = (c + 1 < WH), rp = (r + 1 < HH);
#pragma unroll 4
    for (int ci = 0; ci < 16; ++ci) {
        const float* p = s2 + (long)ci * NPH + (long)r * WH + c;
        float v00 = p[0];
        float v01 = cp ? p[1] : 0.f;
        float v10 = rp ? p[WH] : 0.f;
        float v11 = (rp && cp) ? p[WH + 1] : 0.f;
        const float* wp = w + ci * 8 * 9;
#pragma unroll
        for (int j = 0; j < 8; ++j) {
            const float* wc = wp + j * 9;
            a00[j] = fmaf(v00, wc[4], a00[j]);
            a01[j] = fmaf(v01, wc[3], fmaf(v00, wc[5], a01[j]));
            a10[j] = fmaf(v10, wc[1], fmaf(v00, wc[7], a10[j]));
            a11[j] = fmaf(v11, wc[0], fmaf(v10, wc[2], fmaf(v01, wc[6], fmaf(v00, wc[8], a11[j]))));
        }
    }
    const long o0 = (long)(2 * r) * WF + 2 * c;
#pragma unroll
    for (int j = 0; j < 8; ++j) {
        long o = (long)j * NPF + o0;
        ubuf[o]          = fmaxf(a00[j] + s1[o], 0.f);
        ubuf[o + 1]      = fmaxf(a01[j] + s1[o + 1], 0.f);
        ubuf[o + WF]     = fmaxf(a10[j] + s1[o + WF], 0.f);
        ubuf[o + WF + 1] = fmaxf(a11[j] + s1[o + WF + 1], 0.f);
    }
}

// up2: ConvTranspose2d(8->1, k=3, s=2, p=1, op=1) on u (8,HF,WF) -> out slice (512,640).
// Batched over blockIdx.z. w layout (I=8, O=1, 3, 3).
__global__ __launch_bounds__(256) void k_up2(
    const float* __restrict__ uin, long udstride,
    const float* __restrict__ w, const float* __restrict__ b,
    float* __restrict__ out, int d0)
{
    const int q = blockIdx.x * 256 + threadIdx.x;  // < NPF
    const int r = q / WF, c = q - r * WF;
    const float* ub = uin + blockIdx.z * udstride;
    const float b0 = b[0];
    float a00 = b0, a01 = b0, a10 = b0, a11 = b0;
    const bool cp = (c + 1 < WF), rp = (r + 1 < HF);
#pragma unroll
    for (int ci = 0; ci < 8; ++ci) {
        const float* p = ub + (long)ci * NPF + (long)r * WF + c;
        float v00 = p[0];
        float v01 = cp ? p[1] : 0.f;
        float v10 = rp ? p[WF] : 0.f;
        float v11 = (rp && cp) ? p[WF + 1] : 0.f;
        const float* wc = w + ci * 9;
        a00 = fmaf(v00, wc[4], a00);
        a01 = fmaf(v01, wc[3], fmaf(v00, wc[5], a01));
        a10 = fmaf(v10, wc[1], fmaf(v00, wc[7], a10));
        a11 = fmaf(v11, wc[0], fmaf(v10, wc[2], fmaf(v01, wc[6], fmaf(v00, wc[8], a11))));
    }
    const long d = d0 + blockIdx.z;
    float* o = out + d * (long)(512 * 640) + (long)(2 * r) * 640 + 2 * c;
    o[0] = a00; o[1] = a01; o[640] = a10; o[641] = a11;
}

extern "C" void kernel_launch(void* const* d_in, const int* in_sizes, int n_in,
                              void* d_out, int out_size, void* d_ws, size_t ws_size,
                              hipStream_t stream)
{
    const float* x   = (const float*)d_in[0];
    const float* w1  = (const float*)d_in[1];
    const float* b1  = (const float*)d_in[2];
    const float* wg1 = (const float*)d_in[3];
    const float* bg1 = (const float*)d_in[4];
    const float* wc1 = (const float*)d_in[5];
    const float* bc1 = (const float*)d_in[6];
    const float* w2  = (const float*)d_in[7];
    const float* b2  = (const float*)d_in[8];
    const float* wg2 = (const float*)d_in[9];
    const float* bg2 = (const float*)d_in[10];
    const float* wc2 = (const float*)d_in[11];
    const float* bc2 = (const float*)d_in[12];
    const float* wu1 = (const float*)d_in[13];
    const float* bu1 = (const float*)d_in[14];
    const float* wu2 = (const float*)d_in[15];
    const float* bu2 = (const float*)d_in[16];
    float* out = (float*)d_out;

    float* ws = (float*)d_ws;
    long off = 0;
    float* s1  = ws + off; off += 8L * NPF;
    float* s2  = ws + off; off += 16L * NPH;
    float* rh1 = ws + off; off += 8L * NPF;
    float* ug1 = ws + off; off += 8L * NPF;
    float* c2  = ws + off; off += 16L * NPH;
    float* rh2 = ws + off; off += 16L * NPH;
    float* ug2 = ws + off; off += 16L * NPH;
    float* c1s = ws + off; off += 8L * NPF;   // per-step fallback
    float* us  = ws + off; off += 8L * NPF;   // per-step fallback
    float* c1_all = ws + off;
    float* u_all  = c1_all + 48L * 8L * NPF;
    const size_t need_batched = (size_t)(off + 2L * 48L * 8L * NPF) * sizeof(float);
    const bool batched = ws_size >= need_batched;

    hipMemsetAsync(s1, 0, (size_t)8 * NPF * sizeof(float), stream);
    hipMemsetAsync(s2, 0, (size_t)16 * NPH * sizeof(float), stream);

    if (batched)
        k_conv1<<<dim3(320, 1, 48), 256, 0, stream>>>(x, w1, b1, c1_all, 0, 8L * NPF);

    for (int d = 0; d < 48; ++d) {
        float* c1 = batched ? (c1_all + (long)d * 8L * NPF) : c1s;
        if (!batched)
            k_conv1<<<dim3(320, 1, 1), 256, 0, stream>>>(x, w1, b1, c1, d, 0);

        k_gates<8, HF, WF><<<dim3(320, 2), 256, 0, stream>>>(c1, s1, wg1, bg1, rh1, ug1);
        k_cand <8, HF, WF><<<dim3(320, 1), 256, 0, stream>>>(c1, rh1, wc1, bc1, ug1, s1);
        k_conv2<<<dim3(80, 2), 256, 0, stream>>>(s1, w2, b2, c2);
        k_gates<16, HH, WH><<<dim3(80, 4), 256, 0, stream>>>(c2, s2, wg2, bg2, rh2, ug2);
        k_cand <16, HH, WH><<<dim3(80, 2), 256, 0, stream>>>(c2, rh2, wc2, bc2, ug2, s2);

        float* ub = batched ? (u_all + (long)d * 8L * NPF) : us;
        k_up1<<<dim3(80, 1), 256, 0, stream>>>(s2, wu1, bu1, s1, ub);
        if (!batched)
            k_up2<<<dim3(320, 1, 1), 256, 0, stream>>>(ub, 0, wu2, bu2, out, d);
    }
    if (batched)
        k_up2<<<dim3(320, 1, 48), 256, 0, stream>>>(u_all, 8L * NPF, wu2, bu2, out, 0);
}

// Round 2
// 5102.982 us; speedup vs baseline: 2.0356x; 2.0356x over previous
//
#include <hip/hip_runtime.h>

#define DD 48
#define HF 256
#define WF 320
#define HH 128
#define WH 160
#define NPF (HF * WF)     // 81920
#define NPH (HH * WH)     // 20480
#define S1SZ (8 * NPF)    // 655360 floats, one s1-class slice
#define S2SZ (16 * NPH)   // 327680 floats, one s2-class slice

__device__ __forceinline__ float sigf(float x) { return 1.0f / (1.0f + __expf(-x)); }
__device__ __forceinline__ float tanh_(float x) {
    float e = __expf(2.0f * x);
    return 1.0f - 2.0f / (e + 1.0f);
}

// Clamped tap offsets + 0/1 float masks for a 3x3 window whose top-left input
// coord is (iy0, ix0). Loads are always in-bounds (clamped) -> unconditional,
// no divergent if/endif; OOB taps multiplied by 0.
struct Taps { int off[9]; float m[9]; };

template<int Ht, int Wt>
__device__ __forceinline__ Taps make_taps(int iy0, int ix0) {
    Taps t;
#pragma unroll
    for (int r = 0; r < 3; ++r) {
        int yy = iy0 + r;
        bool rv = (unsigned)yy < (unsigned)Ht;
        int yc = min(max(yy, 0), Ht - 1);
#pragma unroll
        for (int c = 0; c < 3; ++c) {
            int xv = ix0 + c;
            bool cv = (unsigned)xv < (unsigned)Wt;
            int xc = min(max(xv, 0), Wt - 1);
            t.off[r * 3 + c] = yc * Wt + xc;
            t.m[r * 3 + c] = (rv && cv) ? 1.0f : 0.0f;
        }
    }
    return t;
}

// acc[j] += sum_ci sum_k in[ci][off k] * w[(co0+j)][ci][k]
// w points at w[co0][ci_base][0]; wcs = element stride between couts.
// Weight indices are wave-uniform -> scalar loads. unroll 2: ILP without spills.
template<int CI, int COUT>
__device__ __forceinline__ void acc3x3(
    const float* __restrict__ in, int cstride,
    const float* __restrict__ w, int wcs,
    const Taps& t, float* acc)
{
#pragma unroll 2
    for (int ci = 0; ci < CI; ++ci) {
        const float* p = in + ci * cstride;
        float v[9];
#pragma unroll
        for (int k = 0; k < 9; ++k) v[k] = p[t.off[k]] * t.m[k];
        const float* wp = w + ci * 9;
#pragma unroll
        for (int j = 0; j < COUT; ++j) {
            const float* wc = wp + j * wcs;
#pragma unroll
            for (int k = 0; k < 9; ++k) acc[j] = fmaf(v[k], wc[k], acc[j]);
        }
    }
}

// conv1: x slice (d0+z) (32 ch, ch-stride DD*NPF) -> relu -> out+z*ostride (8,HF,WF)
__global__ __launch_bounds__(256) void k_conv1(
    const float* __restrict__ x, const float* __restrict__ w,
    const float* __restrict__ b, float* __restrict__ out,
    int d0, int ostride)
{
    const int pix = blockIdx.x * 256 + threadIdx.x;
    const int y = pix / WF, xx = pix - y * WF;
    const float* xin = x + (d0 + blockIdx.z) * NPF;
    Taps t = make_taps<HF, WF>(y - 1, xx - 1);
    float acc[8];
#pragma unroll
    for (int j = 0; j < 8; ++j) acc[j] = b[j];
    acc3x3<32, 8>(xin, DD * NPF, w, 32 * 9, t, acc);
    float* o = out + blockIdx.z * ostride + pix;
#pragma unroll
    for (int j = 0; j < 8; ++j) o[j * NPF] = fmaxf(acc[j], 0.0f);
}

// gates: g = sigmoid(conv(cat(a,s))); chunks co0<C write rh=sig*s, co0>=C write u=sig
template<int C, int Ht, int Wt>
__global__ __launch_bounds__(256) void k_gates(
    const float* __restrict__ a, const float* __restrict__ s,
    const float* __restrict__ w, const float* __restrict__ b,
    float* __restrict__ rh, float* __restrict__ u)
{
    constexpr int NP = Ht * Wt;
    const int pix = blockIdx.x * 256 + threadIdx.x;
    const int y = pix / Wt, xx = pix - y * Wt;
    const int co0 = blockIdx.y * 8;
    Taps t = make_taps<Ht, Wt>(y - 1, xx - 1);
    float acc[8];
#pragma unroll
    for (int j = 0; j < 8; ++j) acc[j] = b[co0 + j];
    acc3x3<C, 8>(a, NP, w + co0 * (2 * C * 9), 2 * C * 9, t, acc);
    acc3x3<C, 8>(s, NP, w + co0 * (2 * C * 9) + C * 9, 2 * C * 9, t, acc);
    if (co0 < C) {
#pragma unroll
        for (int j = 0; j < 8; ++j) {
            int o = (co0 + j) * NP + pix;
            rh[o] = sigf(acc[j]) * s[o];
        }
    } else {
#pragma unroll
        for (int j = 0; j < 8; ++j) {
            int o = (co0 - C + j) * NP + pix;
            u[o] = sigf(acc[j]);
        }
    }
}

// cand + update: c = tanh(conv(cat(a,rh))); sout = u*sprev + (1-u)*c
template<int C, int Ht, int Wt>
__global__ __launch_bounds__(256) void k_cand(
    const float* __restrict__ a, const float* __restrict__ rh,
    const float* __restrict__ w, const float* __restrict__ b,
    const float* __restrict__ u, const float* __restrict__ sprev,
    float* __restrict__ sout)
{
    constexpr int NP = Ht * Wt;
    const int pix = blockIdx.x * 256 + threadIdx.x;
    const int y = pix / Wt, xx = pix - y * Wt;
    const int co0 = blockIdx.y * 8;
    Taps t = make_taps<Ht, Wt>(y - 1, xx - 1);
    float acc[8];
#pragma unroll
    for (int j = 0; j < 8; ++j) acc[j] = b[co0 + j];
    acc3x3<C, 8>(a, NP, w + co0 * (2 * C * 9), 2 * C * 9, t, acc);
    acc3x3<C, 8>(rh, NP, w + co0 * (2 * C * 9) + C * 9, 2 * C * 9, t, acc);
#pragma unroll
    for (int j = 0; j < 8; ++j) {
        int o = (co0 + j) * NP + pix;
        float c = tanh_(acc[j]);
        float uu = u[o];
        sout[o] = fmaf(uu, sprev[o] - c, c);
    }
}

// conv2: stride-2 3x3 pad1, s1 (8,HF,WF) -> relu -> c2 (16,HH,WH); z-batched
__global__ __launch_bounds__(256) void k_conv2(
    const float* __restrict__ s1b, int zs1,
    const float* __restrict__ w, const float* __restrict__ b,
    float* __restrict__ c2b, int zc2)
{
    const int pix = blockIdx.x * 256 + threadIdx.x;  // < NPH
    const int y = pix / WH, xx = pix - y * WH;
    const int co0 = blockIdx.y * 8;
    const float* s1 = s1b + blockIdx.z * zs1;
    float* c2 = c2b + blockIdx.z * zc2;
    Taps t = make_taps<HF, WF>(2 * y - 1, 2 * xx - 1);
    float acc[8];
#pragma unroll
    for (int j = 0; j < 8; ++j) acc[j] = b[co0 + j];
    acc3x3<8, 8>(s1, NPF, w + co0 * (8 * 9), 8 * 9, t, acc);
#pragma unroll
    for (int j = 0; j < 8; ++j) c2[(co0 + j) * NPH + pix] = fmaxf(acc[j], 0.0f);
}

// up1: ConvTranspose2d(16->8,k3,s2,p1,op1) + s1 skip + relu -> u; z-batched.
// One thread = one 2x2 output quad. w layout (I=16,O=8,3,3).
__global__ __launch_bounds__(256) void k_up1(
    const float* __restrict__ s2b, int zs2,
    const float* __restrict__ w, const float* __restrict__ b,
    const float* __restrict__ s1b, int zs1,
    float* __restrict__ ub, int zu)
{
    const int q = blockIdx.x * 256 + threadIdx.x;  // < NPH
    const int r = q / WH, c = q - r * WH;
    const float* s2 = s2b + blockIdx.z * zs2;
    const float* s1 = s1b + blockIdx.z * zs1;
    float* ubuf = ub + blockIdx.z * zu;
    const int dc = (c + 1 < WH) ? 1 : 0;
    const int dr = (r + 1 < HH) ? WH : 0;
    const float mc = (c + 1 < WH) ? 1.0f : 0.0f;
    const float mr = (r + 1 < HH) ? 1.0f : 0.0f;
    const float mrc = mc * mr;
    float a00[8], a01[8], a10[8], a11[8];
#pragma unroll
    for (int j = 0; j < 8; ++j) { a00[j] = b[j]; a01[j] = b[j]; a10[j] = b[j]; a11[j] = b[j]; }
#pragma unroll 2
    for (int ci = 0; ci < 16; ++ci) {
        const float* p = s2 + ci * NPH + r * WH + c;
        float v00 = p[0];
        float v01 = p[dc] * mc;
        float v10 = p[dr] * mr;
        float v11 = p[dr + dc] * mrc;
        const float* wp = w + ci * 8 * 9;
#pragma unroll
        for (int j = 0; j < 8; ++j) {
            const float* wc = wp + j * 9;
            a00[j] = fmaf(v00, wc[4], a00[j]);
            a01[j] = fmaf(v01, wc[3], fmaf(v00, wc[5], a01[j]));
            a10[j] = fmaf(v10, wc[1], fmaf(v00, wc[7], a10[j]));
            a11[j] = fmaf(v11, wc[0], fmaf(v10, wc[2], fmaf(v01, wc[6], fmaf(v00, wc[8], a11[j]))));
        }
    }
    const int o0 = (2 * r) * WF + 2 * c;
#pragma unroll
    for (int j = 0; j < 8; ++j) {
        int o = j * NPF + o0;
        ubuf[o]          = fmaxf(a00[j] + s1[o], 0.0f);
        ubuf[o + 1]      = fmaxf(a01[j] + s1[o + 1], 0.0f);
        ubuf[o + WF]     = fmaxf(a10[j] + s1[o + WF], 0.0f);
        ubuf[o + WF + 1] = fmaxf(a11[j] + s1[o + WF + 1], 0.0f);
    }
}

// up2: ConvTranspose2d(8->1,k3,s2,p1,op1): u (8,HF,WF) -> out slice (512,640); z-batched
__global__ __launch_bounds__(256) void k_up2(
    const float* __restrict__ ub, int zu,
    const float* __restrict__ w, const float* __restrict__ b,
    float* __restrict__ out, int d0)
{
    const int q = blockIdx.x * 256 + threadIdx.x;  // < NPF
    const int r = q / WF, c = q - r * WF;
    const float* u = ub + blockIdx.z * zu;
    const int dc = (c + 1 < WF) ? 1 : 0;
    const int dr = (r + 1 < HF) ? WF : 0;
    const float mc = (c + 1 < WF) ? 1.0f : 0.0f;
    const float mr = (r + 1 < HF) ? 1.0f : 0.0f;
    const float mrc = mc * mr;
    const float b0 = b[0];
    float a00 = b0, a01 = b0, a10 = b0, a11 = b0;
#pragma unroll 2
    for (int ci = 0; ci < 8; ++ci) {
        const float* p = u + ci * NPF + r * WF + c;
        float v00 = p[0];
        float v01 = p[dc] * mc;
        float v10 = p[dr] * mr;
        float v11 = p[dr + dc] * mrc;
        const float* wc = w + ci * 9;
        a00 = fmaf(v00, wc[4], a00);
        a01 = fmaf(v01, wc[3], fmaf(v00, wc[5], a01));
        a10 = fmaf(v10, wc[1], fmaf(v00, wc[7], a10));
        a11 = fmaf(v11, wc[0], fmaf(v10, wc[2], fmaf(v01, wc[6], fmaf(v00, wc[8], a11))));
    }
    float* o = out + (long)(d0 + blockIdx.z) * (512 * 640) + (2 * r) * 640 + 2 * c;
    o[0] = a00; o[1] = a01; o[640] = a10; o[641] = a11;
}

extern "C" void kernel_launch(void* const* d_in, const int* in_sizes, int n_in,
                              void* d_out, int out_size, void* d_ws, size_t ws_size,
                              hipStream_t stream)
{
    const float* x   = (const float*)d_in[0];
    const float* w1  = (const float*)d_in[1];
    const float* b1  = (const float*)d_in[2];
    const float* wg1 = (const float*)d_in[3];
    const float* bg1 = (const float*)d_in[4];
    const float* wc1 = (const float*)d_in[5];
    const float* bc1 = (const float*)d_in[6];
    const float* w2  = (const float*)d_in[7];
    const float* b2  = (const float*)d_in[8];
    const float* wg2 = (const float*)d_in[9];
    const float* bg2 = (const float*)d_in[10];
    const float* wc2 = (const float*)d_in[11];
    const float* bc2 = (const float*)d_in[12];
    const float* wu1 = (const float*)d_in[13];
    const float* bu1 = (const float*)d_in[14];
    const float* wu2 = (const float*)d_in[15];
    const float* bu2 = (const float*)d_in[16];
    float* out = (float*)d_out;
    float* ws = (float*)d_ws;

    // ---- full-history layout (separated chains + batched conv2/up1/up2) ----
    {
        float* p = ws;
        float* s1_all = p; p += 49L * S1SZ;   // slice 0 = zeros (state d=-1)
        float* s2_all = p; p += 49L * S2SZ;
        float* c2_all = p; p += 48L * S2SZ;
        float* rh1 = p; p += S1SZ;
        float* ug1 = p; p += S1SZ;
        float* rh2 = p; p += S2SZ;
        float* ug2 = p; p += S2SZ;
        float* c1_all = p; p += 48L * S1SZ;   // later reused as u_all
        const size_t need = (size_t)(p - ws) * sizeof(float);
        if (ws_size >= need) {
            float* u_all = c1_all;
            hipMemsetAsync(s1_all, 0, (size_t)S1SZ * sizeof(float), stream);
            hipMemsetAsync(s2_all, 0, (size_t)S2SZ * sizeof(float), stream);

            // A: conv1 for all d (full chip)
            k_conv1<<<dim3(320, 1, 48), 256, 0, stream>>>(x, w1, b1, c1_all, 0, S1SZ);
            // B: s1 GRU chain
            for (int d = 0; d < 48; ++d) {
                const float* c1 = c1_all + (long)d * S1SZ;
                const float* sp = s1_all + (long)d * S1SZ;
                float* sn = s1_all + (long)(d + 1) * S1SZ;
                k_gates<8, HF, WF><<<dim3(320, 2), 256, 0, stream>>>(c1, sp, wg1, bg1, rh1, ug1);
                k_cand <8, HF, WF><<<dim3(320, 1), 256, 0, stream>>>(c1, rh1, wc1, bc1, ug1, sp, sn);
            }
            // C: conv2 for all d (full chip)
            k_conv2<<<dim3(80, 2, 48), 256, 0, stream>>>(s1_all + S1SZ, S1SZ, w2, b2, c2_all, S2SZ);
            // D: s2 GRU chain
            for (int d = 0; d < 48; ++d) {
                const float* c2 = c2_all + (long)d * S2SZ;
                const float* sp = s2_all + (long)d * S2SZ;
                float* sn = s2_all + (long)(d + 1) * S2SZ;
                k_gates<16, HH, WH><<<dim3(80, 4), 256, 0, stream>>>(c2, sp, wg2, bg2, rh2, ug2);
                k_cand <16, HH, WH><<<dim3(80, 2), 256, 0, stream>>>(c2, rh2, wc2, bc2, ug2, sp, sn);
            }
            // E: up1 for all d (c1_all is dead; reuse as u_all)
            k_up1<<<dim3(80, 1, 48), 256, 0, stream>>>(s2_all + S2SZ, S2SZ, wu1, bu1,
                                                       s1_all + S1SZ, S1SZ, u_all, S1SZ);
            // F: up2 for all d
            k_up2<<<dim3(320, 1, 48), 256, 0, stream>>>(u_all, S1SZ, wu2, bu2, out, 0);
            return;
        }
    }

    // ---- fallback: small-workspace interleaved schedule ----
    {
        float* p = ws;
        float* s1 = p; p += S1SZ;
        float* s2 = p; p += S2SZ;
        float* rh1 = p; p += S1SZ;
        float* ug1 = p; p += S1SZ;
        float* c2 = p; p += S2SZ;
        float* rh2 = p; p += S2SZ;
        float* ug2 = p; p += S2SZ;
        float* c1 = p; p += S1SZ;
        float* u = p; p += S1SZ;
        hipMemsetAsync(s1, 0, (size_t)S1SZ * sizeof(float), stream);
        hipMemsetAsync(s2, 0, (size_t)S2SZ * sizeof(float), stream);
        for (int d = 0; d < 48; ++d) {
            k_conv1<<<dim3(320, 1, 1), 256, 0, stream>>>(x, w1, b1, c1, d, 0);
            k_gates<8, HF, WF><<<dim3(320, 2), 256, 0, stream>>>(c1, s1, wg1, bg1, rh1, ug1);
            k_cand <8, HF, WF><<<dim3(320, 1), 256, 0, stream>>>(c1, rh1, wc1, bc1, ug1, s1, s1);
            k_conv2<<<dim3(80, 2, 1), 256, 0, stream>>>(s1, 0, w2, b2, c2, 0);
            k_gates<16, HH, WH><<<dim3(80, 4), 256, 0, stream>>>(c2, s2, wg2, bg2, rh2, ug2);
            k_cand <16, HH, WH><<<dim3(80, 2), 256, 0, stream>>>(c2, rh2, wc2, bc2, ug2, s2, s2);
            k_up1<<<dim3(80, 1, 1), 256, 0, stream>>>(s2, 0, wu1, bu1, s1, 0, u, 0);
            k_up2<<<dim3(320, 1, 1), 256, 0, stream>>>(u, 0, wu2, bu2, out, d);
        }
    }
}

// Round 3
// 5087.074 us; speedup vs baseline: 2.0419x; 1.0031x over previous
//
#include <hip/hip_runtime.h>

#define DD 48
#define HF 256
#define WF 320
#define HH 128
#define WH 160
#define NPF (HF * WF)     // 81920
#define NPH (HH * WH)     // 20480
#define S1SZ (8 * NPF)    // one s1-class slice (floats)
#define S2SZ (16 * NPH)   // one s2-class slice (floats)

__device__ __forceinline__ float sigf(float x) { return 1.0f / (1.0f + __expf(-x)); }
__device__ __forceinline__ float tanh_(float x) {
    float e = __expf(2.0f * x);
    return 1.0f - 2.0f / (e + 1.0f);
}

// ---- 2-px conv core -------------------------------------------------------
// Thread computes output pixels (y, x0) and (y, x0+1), x0 even (W even => a
// linear even/odd pair never straddles a row). Per input channel the 3x4
// window is 12 unconditional clamped loads (masked by 0/1 floats) feeding
// 2px * COUT * 9 FMAs.

template<int Ht, int Wt>
__device__ __forceinline__ void taps2(int y, int x0, int* off, float* msk) {
    int cx[4]; float cm[4];
    cx[0] = max(x0 - 1, 0);      cm[0] = (x0 > 0) ? 1.0f : 0.0f;
    cx[1] = x0;                  cm[1] = 1.0f;
    cx[2] = x0 + 1;              cm[2] = 1.0f;                      // x0+1 <= Wt-1 always
    cx[3] = min(x0 + 2, Wt - 1); cm[3] = (x0 + 2 < Wt) ? 1.0f : 0.0f;
#pragma unroll
    for (int r = 0; r < 3; ++r) {
        int yy = y - 1 + r;
        float rm = ((unsigned)yy < (unsigned)Ht) ? 1.0f : 0.0f;
        int rb = min(max(yy, 0), Ht - 1) * Wt;
#pragma unroll
        for (int k = 0; k < 4; ++k) {
            off[r * 4 + k] = rb + cx[k];
            msk[r * 4 + k] = rm * cm[k];
        }
    }
}

// acc 2 px x COUT over CI channels. w points at w[cout0][ci0][0][0]; wcs =
// element stride between consecutive couts (wave-uniform -> scalar loads).
template<int CI, int COUT>
__device__ __forceinline__ void acc2px(
    const float* __restrict__ in, int cs,
    const float* __restrict__ w, int wcs,
    const int* off, const float* msk,
    float* a0, float* a1)
{
#pragma unroll 2
    for (int ci = 0; ci < CI; ++ci) {
        const float* p = in + ci * cs;
        float v[12];
#pragma unroll
        for (int k = 0; k < 12; ++k) v[k] = p[off[k]] * msk[k];
        const float* wp = w + ci * 9;
#pragma unroll
        for (int j = 0; j < COUT; ++j) {
            const float* wc = wp + j * wcs;
#pragma unroll
            for (int r = 0; r < 3; ++r) {
                a0[j] = fmaf(v[r * 4 + 0], wc[r * 3 + 0], a0[j]);
                a0[j] = fmaf(v[r * 4 + 1], wc[r * 3 + 1], a0[j]);
                a0[j] = fmaf(v[r * 4 + 2], wc[r * 3 + 2], a0[j]);
                a1[j] = fmaf(v[r * 4 + 1], wc[r * 3 + 0], a1[j]);
                a1[j] = fmaf(v[r * 4 + 2], wc[r * 3 + 1], a1[j]);
                a1[j] = fmaf(v[r * 4 + 3], wc[r * 3 + 2], a1[j]);
            }
        }
    }
}

// ---- conv1: x slice (d0+z), 32 ch (ch-stride DD*NPF) -> relu -> 8 ch ------
__global__ __launch_bounds__(256) void k_conv1(
    const float* __restrict__ x, const float* __restrict__ w,
    const float* __restrict__ b, float* __restrict__ out,
    int d0, int ostride)
{
    const int pix0 = (blockIdx.x * 256 + threadIdx.x) * 2;
    const int y = pix0 / WF, x0 = pix0 - y * WF;
    const float* xin = x + (d0 + blockIdx.z) * NPF;
    int off[12]; float msk[12];
    taps2<HF, WF>(y, x0, off, msk);
    float a0[8], a1[8];
#pragma unroll
    for (int j = 0; j < 8; ++j) { a0[j] = b[j]; a1[j] = b[j]; }
    acc2px<32, 8>(xin, DD * NPF, w, 32 * 9, off, msk, a0, a1);
    float* o = out + blockIdx.z * ostride + pix0;
#pragma unroll
    for (int j = 0; j < 8; ++j) {
        o[j * NPF]     = fmaxf(a0[j], 0.0f);
        o[j * NPF + 1] = fmaxf(a1[j], 0.0f);
    }
}

// ---- gates: g = sigmoid(conv(cat(a,s))); co0<C -> rh = sig*s, else u ------
template<int C, int Ht, int Wt>
__global__ __launch_bounds__(256) void k_gates(
    const float* __restrict__ a, const float* __restrict__ s,
    const float* __restrict__ w, const float* __restrict__ b,
    float* __restrict__ rh, float* __restrict__ u)
{
    constexpr int NP = Ht * Wt;
    const int pix0 = (blockIdx.x * 256 + threadIdx.x) * 2;
    const int y = pix0 / Wt, x0 = pix0 - y * Wt;
    const int co0 = blockIdx.y * 8;
    int off[12]; float msk[12];
    taps2<Ht, Wt>(y, x0, off, msk);
    float a0[8], a1[8];
#pragma unroll
    for (int j = 0; j < 8; ++j) { a0[j] = b[co0 + j]; a1[j] = b[co0 + j]; }
    acc2px<C, 8>(a, NP, w + co0 * (2 * C * 9), 2 * C * 9, off, msk, a0, a1);
    acc2px<C, 8>(s, NP, w + co0 * (2 * C * 9) + C * 9, 2 * C * 9, off, msk, a0, a1);
    if (co0 < C) {
#pragma unroll
        for (int j = 0; j < 8; ++j) {
            int o = (co0 + j) * NP + pix0;
            rh[o]     = sigf(a0[j]) * s[o];
            rh[o + 1] = sigf(a1[j]) * s[o + 1];
        }
    } else {
#pragma unroll
        for (int j = 0; j < 8; ++j) {
            int o = (co0 - C + j) * NP + pix0;
            u[o]     = sigf(a0[j]);
            u[o + 1] = sigf(a1[j]);
        }
    }
}

// ---- cand + update: c = tanh(conv(cat(a,rh))); sout = u*sprev + (1-u)*c ---
template<int C, int Ht, int Wt>
__global__ __launch_bounds__(256) void k_cand(
    const float* __restrict__ a, const float* __restrict__ rh,
    const float* __restrict__ w, const float* __restrict__ b,
    const float* __restrict__ u, const float* __restrict__ sprev,
    float* __restrict__ sout)
{
    constexpr int NP = Ht * Wt;
    const int pix0 = (blockIdx.x * 256 + threadIdx.x) * 2;
    const int y = pix0 / Wt, x0 = pix0 - y * Wt;
    const int co0 = blockIdx.y * 8;
    int off[12]; float msk[12];
    taps2<Ht, Wt>(y, x0, off, msk);
    float a0[8], a1[8];
#pragma unroll
    for (int j = 0; j < 8; ++j) { a0[j] = b[co0 + j]; a1[j] = b[co0 + j]; }
    acc2px<C, 8>(a, NP, w + co0 * (2 * C * 9), 2 * C * 9, off, msk, a0, a1);
    acc2px<C, 8>(rh, NP, w + co0 * (2 * C * 9) + C * 9, 2 * C * 9, off, msk, a0, a1);
#pragma unroll
    for (int j = 0; j < 8; ++j) {
        int o = (co0 + j) * NP + pix0;
        float c0 = tanh_(a0[j]);
        float c1 = tanh_(a1[j]);
        sout[o]     = fmaf(u[o],     sprev[o]     - c0, c0);
        sout[o + 1] = fmaf(u[o + 1], sprev[o + 1] - c1, c1);
    }
}

// ---- conv2: stride-2 3x3 pad1, (8,HF,WF) -> relu -> (16,HH,WH); 2px out ---
__global__ __launch_bounds__(256) void k_conv2(
    const float* __restrict__ s1b, int zs1,
    const float* __restrict__ w, const float* __restrict__ b,
    float* __restrict__ c2b, int zc2)
{
    const int pix0 = (blockIdx.x * 256 + threadIdx.x) * 2;  // output px in NPH
    const int y = pix0 / WH, x0 = pix0 - y * WH;            // x0 even, <= WH-2
    const int co0 = blockIdx.y * 8;
    const float* s1 = s1b + blockIdx.z * zs1;
    float* c2 = c2b + blockIdx.z * zc2;
    // input window: rows 2y-1..2y+1, cols 2x0-1..2x0+3 (5 cols)
    int off[15]; float msk[15];
    {
        int cx[5]; float cm[5];
        cx[0] = max(2 * x0 - 1, 0); cm[0] = (x0 > 0) ? 1.0f : 0.0f;
#pragma unroll
        for (int i = 1; i < 5; ++i) { cx[i] = 2 * x0 - 1 + i; cm[i] = 1.0f; }
#pragma unroll
        for (int r = 0; r < 3; ++r) {
            int yy = 2 * y - 1 + r;
            float rm = ((unsigned)yy < (unsigned)HF) ? 1.0f : 0.0f;
            int rb = min(max(yy, 0), HF - 1) * WF;
#pragma unroll
            for (int i = 0; i < 5; ++i) { off[r * 5 + i] = rb + cx[i]; msk[r * 5 + i] = rm * cm[i]; }
        }
    }
    float a0[8], a1[8];
#pragma unroll
    for (int j = 0; j < 8; ++j) { a0[j] = b[co0 + j]; a1[j] = b[co0 + j]; }
#pragma unroll 2
    for (int ci = 0; ci < 8; ++ci) {
        const float* p = s1 + ci * NPF;
        float v[15];
#pragma unroll
        for (int k = 0; k < 15; ++k) v[k] = p[off[k]] * msk[k];
        const float* wp = w + co0 * 72 + ci * 9;   // w (16,8,3,3), cout stride 72
#pragma unroll
        for (int j = 0; j < 8; ++j) {
            const float* wc = wp + j * 72;
#pragma unroll
            for (int r = 0; r < 3; ++r) {
                a0[j] = fmaf(v[r * 5 + 0], wc[r * 3 + 0], a0[j]);
                a0[j] = fmaf(v[r * 5 + 1], wc[r * 3 + 1], a0[j]);
                a0[j] = fmaf(v[r * 5 + 2], wc[r * 3 + 2], a0[j]);
                a1[j] = fmaf(v[r * 5 + 2], wc[r * 3 + 0], a1[j]);
                a1[j] = fmaf(v[r * 5 + 3], wc[r * 3 + 1], a1[j]);
                a1[j] = fmaf(v[r * 5 + 4], wc[r * 3 + 2], a1[j]);
            }
        }
    }
#pragma unroll
    for (int j = 0; j < 8; ++j) {
        c2[(co0 + j) * NPH + pix0]     = fmaxf(a0[j], 0.0f);
        c2[(co0 + j) * NPH + pix0 + 1] = fmaxf(a1[j], 0.0f);
    }
}

// ---- up1: ConvTranspose2d(16->8,k3,s2,p1,op1) + s1 skip + relu ------------
__global__ __launch_bounds__(256) void k_up1(
    const float* __restrict__ s2b, int zs2,
    const float* __restrict__ w, const float* __restrict__ b,
    const float* __restrict__ s1b, int zs1,
    float* __restrict__ ub, int zu)
{
    const int q = blockIdx.x * 256 + threadIdx.x;  // < NPH
    const int r = q / WH, c = q - r * WH;
    const float* s2 = s2b + blockIdx.z * zs2;
    const float* s1 = s1b + blockIdx.z * zs1;
    float* ubuf = ub + blockIdx.z * zu;
    const int dc = (c + 1 < WH) ? 1 : 0;
    const int dr = (r + 1 < HH) ? WH : 0;
    const float mc = (c + 1 < WH) ? 1.0f : 0.0f;
    const float mr = (r + 1 < HH) ? 1.0f : 0.0f;
    const float mrc = mc * mr;
    float a00[8], a01[8], a10[8], a11[8];
#pragma unroll
    for (int j = 0; j < 8; ++j) { a00[j] = b[j]; a01[j] = b[j]; a10[j] = b[j]; a11[j] = b[j]; }
#pragma unroll 2
    for (int ci = 0; ci < 16; ++ci) {
        const float* p = s2 + ci * NPH + r * WH + c;
        float v00 = p[0];
        float v01 = p[dc] * mc;
        float v10 = p[dr] * mr;
        float v11 = p[dr + dc] * mrc;
        const float* wp = w + ci * 8 * 9;
#pragma unroll
        for (int j = 0; j < 8; ++j) {
            const float* wc = wp + j * 9;
            a00[j] = fmaf(v00, wc[4], a00[j]);
            a01[j] = fmaf(v01, wc[3], fmaf(v00, wc[5], a01[j]));
            a10[j] = fmaf(v10, wc[1], fmaf(v00, wc[7], a10[j]));
            a11[j] = fmaf(v11, wc[0], fmaf(v10, wc[2], fmaf(v01, wc[6], fmaf(v00, wc[8], a11[j]))));
        }
    }
    const int o0 = (2 * r) * WF + 2 * c;
#pragma unroll
    for (int j = 0; j < 8; ++j) {
        int o = j * NPF + o0;
        ubuf[o]          = fmaxf(a00[j] + s1[o], 0.0f);
        ubuf[o + 1]      = fmaxf(a01[j] + s1[o + 1], 0.0f);
        ubuf[o + WF]     = fmaxf(a10[j] + s1[o + WF], 0.0f);
        ubuf[o + WF + 1] = fmaxf(a11[j] + s1[o + WF + 1], 0.0f);
    }
}

// ---- up2: ConvTranspose2d(8->1,k3,s2,p1,op1) -> out slice (512,640) -------
__global__ __launch_bounds__(256) void k_up2(
    const float* __restrict__ ub, int zu,
    const float* __restrict__ w, const float* __restrict__ b,
    float* __restrict__ out, int d0)
{
    const int q = blockIdx.x * 256 + threadIdx.x;  // < NPF
    const int r = q / WF, c = q - r * WF;
    const float* u = ub + blockIdx.z * zu;
    const int dc = (c + 1 < WF) ? 1 : 0;
    const int dr = (r + 1 < HF) ? WF : 0;
    const float mc = (c + 1 < WF) ? 1.0f : 0.0f;
    const float mr = (r + 1 < HF) ? 1.0f : 0.0f;
    const float mrc = mc * mr;
    const float b0 = b[0];
    float a00 = b0, a01 = b0, a10 = b0, a11 = b0;
#pragma unroll 2
    for (int ci = 0; ci < 8; ++ci) {
        const float* p = u + ci * NPF + r * WF + c;
        float v00 = p[0];
        float v01 = p[dc] * mc;
        float v10 = p[dr] * mr;
        float v11 = p[dr + dc] * mrc;
        const float* wc = w + ci * 9;
        a00 = fmaf(v00, wc[4], a00);
        a01 = fmaf(v01, wc[3], fmaf(v00, wc[5], a01));
        a10 = fmaf(v10, wc[1], fmaf(v00, wc[7], a10));
        a11 = fmaf(v11, wc[0], fmaf(v10, wc[2], fmaf(v01, wc[6], fmaf(v00, wc[8], a11))));
    }
    float* o = out + (long)(d0 + blockIdx.z) * (512 * 640) + (2 * r) * 640 + 2 * c;
    o[0] = a00; o[1] = a01; o[640] = a10; o[641] = a11;
}

extern "C" void kernel_launch(void* const* d_in, const int* in_sizes, int n_in,
                              void* d_out, int out_size, void* d_ws, size_t ws_size,
                              hipStream_t stream)
{
    const float* x   = (const float*)d_in[0];
    const float* w1  = (const float*)d_in[1];
    const float* b1  = (const float*)d_in[2];
    const float* wg1 = (const float*)d_in[3];
    const float* bg1 = (const float*)d_in[4];
    const float* wc1 = (const float*)d_in[5];
    const float* bc1 = (const float*)d_in[6];
    const float* w2  = (const float*)d_in[7];
    const float* b2  = (const float*)d_in[8];
    const float* wg2 = (const float*)d_in[9];
    const float* bg2 = (const float*)d_in[10];
    const float* wc2 = (const float*)d_in[11];
    const float* bc2 = (const float*)d_in[12];
    const float* wu1 = (const float*)d_in[13];
    const float* bu1 = (const float*)d_in[14];
    const float* wu2 = (const float*)d_in[15];
    const float* bu2 = (const float*)d_in[16];
    float* out = (float*)d_out;
    float* ws = (float*)d_ws;

    // ---- full-history schedule (separated chains + batched bulk work) ----
    {
        float* p = ws;
        float* s1_all = p; p += 49L * S1SZ;   // slice 0 = zeros
        float* s2_all = p; p += 49L * S2SZ;
        float* c2_all = p; p += 48L * S2SZ;
        float* rh1 = p; p += S1SZ;
        float* ug1 = p; p += S1SZ;
        float* rh2 = p; p += S2SZ;
        float* ug2 = p; p += S2SZ;
        float* c1_all = p; p += 48L * S1SZ;   // reused as u_all after s1 chain
        const size_t need = (size_t)(p - ws) * sizeof(float);
        if (ws_size >= need) {
            float* u_all = c1_all;
            hipMemsetAsync(s1_all, 0, (size_t)S1SZ * sizeof(float), stream);
            hipMemsetAsync(s2_all, 0, (size_t)S2SZ * sizeof(float), stream);

            k_conv1<<<dim3(160, 1, 48), 256, 0, stream>>>(x, w1, b1, c1_all, 0, S1SZ);
            for (int d = 0; d < 48; ++d) {
                const float* c1 = c1_all + (long)d * S1SZ;
                const float* sp = s1_all + (long)d * S1SZ;
                float* sn = s1_all + (long)(d + 1) * S1SZ;
                k_gates<8, HF, WF><<<dim3(160, 2), 256, 0, stream>>>(c1, sp, wg1, bg1, rh1, ug1);
                k_cand <8, HF, WF><<<dim3(160, 1), 256, 0, stream>>>(c1, rh1, wc1, bc1, ug1, sp, sn);
            }
            k_conv2<<<dim3(40, 2, 48), 256, 0, stream>>>(s1_all + S1SZ, S1SZ, w2, b2, c2_all, S2SZ);
            for (int d = 0; d < 48; ++d) {
                const float* c2 = c2_all + (long)d * S2SZ;
                const float* sp = s2_all + (long)d * S2SZ;
                float* sn = s2_all + (long)(d + 1) * S2SZ;
                k_gates<16, HH, WH><<<dim3(40, 4), 256, 0, stream>>>(c2, sp, wg2, bg2, rh2, ug2);
                k_cand <16, HH, WH><<<dim3(40, 2), 256, 0, stream>>>(c2, rh2, wc2, bc2, ug2, sp, sn);
            }
            k_up1<<<dim3(80, 1, 48), 256, 0, stream>>>(s2_all + S2SZ, S2SZ, wu1, bu1,
                                                       s1_all + S1SZ, S1SZ, u_all, S1SZ);
            k_up2<<<dim3(320, 1, 48), 256, 0, stream>>>(u_all, S1SZ, wu2, bu2, out, 0);
            return;
        }
    }

    // ---- fallback: small-workspace interleaved schedule ----
    {
        float* p = ws;
        float* s1 = p; p += S1SZ;
        float* s2 = p; p += S2SZ;
        float* rh1 = p; p += S1SZ;
        float* ug1 = p; p += S1SZ;
        float* c2 = p; p += S2SZ;
        float* rh2 = p; p += S2SZ;
        float* ug2 = p; p += S2SZ;
        float* c1 = p; p += S1SZ;
        float* u = p; p += S1SZ;
        hipMemsetAsync(s1, 0, (size_t)S1SZ * sizeof(float), stream);
        hipMemsetAsync(s2, 0, (size_t)S2SZ * sizeof(float), stream);
        for (int d = 0; d < 48; ++d) {
            k_conv1<<<dim3(160, 1, 1), 256, 0, stream>>>(x, w1, b1, c1, d, 0);
            k_gates<8, HF, WF><<<dim3(160, 2), 256, 0, stream>>>(c1, s1, wg1, bg1, rh1, ug1);
            k_cand <8, HF, WF><<<dim3(160, 1), 256, 0, stream>>>(c1, rh1, wc1, bc1, ug1, s1, s1);
            k_conv2<<<dim3(40, 2, 1), 256, 0, stream>>>(s1, 0, w2, b2, c2, 0);
            k_gates<16, HH, WH><<<dim3(40, 4), 256, 0, stream>>>(c2, s2, wg2, bg2, rh2, ug2);
            k_cand <16, HH, WH><<<dim3(40, 2), 256, 0, stream>>>(c2, rh2, wc2, bc2, ug2, s2, s2);
            k_up1<<<dim3(80, 1, 1), 256, 0, stream>>>(s2, 0, wu1, bu1, s1, 0, u, 0);
            k_up2<<<dim3(320, 1, 1), 256, 0, stream>>>(u, 0, wu2, bu2, out, d);
        }
    }
}